// Round 3
// baseline (948.173 us; speedup 1.0000x reference)
//
#include <hip/hip_runtime.h>
#include <hip/hip_bf16.h>

#define NV 3
#define NN 20000
#define NTT 60000
#define NE 800000
#define NR 6
#define NB 4
#define DD 128
#define INF 2000
#define NL 5

typedef __attribute__((ext_vector_type(8))) short short8;
typedef __attribute__((ext_vector_type(4))) float f32x4;

__device__ __forceinline__ unsigned short f2bf(float f) {
    unsigned int u = __float_as_uint(f);
    u += 0x7FFFu + ((u >> 16) & 1u);   // RNE
    return (unsigned short)(u >> 16);
}
__device__ __forceinline__ float bf2f(unsigned short h) {
    return __uint_as_float(((unsigned int)h) << 16);
}
// 8 fp32 -> short8 of bf16 via packed converts
__device__ __forceinline__ short8 cvt8(float4 a, float4 b) {
    union { short8 v; __hip_bfloat162 h[4]; } u;
    u.h[0] = __float22bfloat162_rn(make_float2(a.x, a.y));
    u.h[1] = __float22bfloat162_rn(make_float2(a.z, a.w));
    u.h[2] = __float22bfloat162_rn(make_float2(b.x, b.y));
    u.h[3] = __float22bfloat162_rn(make_float2(b.z, b.w));
    return u.v;
}

// ---------- fused small prep: wTrel + qk vectors + zero indeg/cursor ----------
__global__ void prep_misc(const float* __restrict__ basis, const float* __restrict__ comp,
                          const float* __restrict__ att_q, const float* __restrict__ att_k,
                          unsigned short* __restrict__ wTrel, float* __restrict__ qvec,
                          float* __restrict__ kvec, int* __restrict__ indeg,
                          int* __restrict__ cursor) {
    int b = blockIdx.x;
    if (b < 384) {  // wTrel[r][o][d] = bf16(sum_b comp[r][b]*basis[b][d][o])
        int idx = b * 256 + threadIdx.x;
        int r = idx / (DD * DD);
        int rem = idx - r * (DD * DD);
        int o = rem / DD;
        int d = rem - o * DD;
        float s = 0.f;
        #pragma unroll
        for (int bb = 0; bb < NB; bb++)
            s += comp[r * NB + bb] * basis[((size_t)bb * DD + d) * DD + o];
        wTrel[idx] = f2bf(s);
    } else if (b < 390) {  // qvec/kvec[r][d] = sum_o W_r[d][o]*att[o]
        int idx = (b - 384) * 256 + threadIdx.x;
        int sel = idx / (NR * DD);
        int rem = idx - sel * (NR * DD);
        int r = rem / DD;
        int d = rem - r * DD;
        const float* att = sel ? att_k : att_q;
        float s = 0.f;
        #pragma unroll
        for (int bb = 0; bb < NB; bb++) {
            float cb = comp[r * NB + bb];
            float t = 0.f;
            for (int o = 0; o < DD; o++) t += basis[((size_t)bb * DD + d) * DD + o] * att[o];
            s += cb * t;
        }
        (sel ? kvec : qvec)[r * DD + d] = s;
    } else {  // zero indeg + cursor
        int i = (b - 390) * 256 + threadIdx.x;
        if (i < NTT) { indeg[i] = 0; cursor[i] = 0; }
    }
}

// ---------- coalesced W transpose+cvt: wT[v][n][k] = bf16(w_v[k][n]) ----------
__global__ void prep_wTt(const float* __restrict__ w0, const float* __restrict__ w1,
                         const float* __restrict__ w2, unsigned short* __restrict__ wT) {
    __shared__ float tile[32][33];
    int v = blockIdx.z;
    const float* w = (v == 0) ? w0 : ((v == 1) ? w1 : w2);
    int k0 = blockIdx.x * 32, n0 = blockIdx.y * 32;
    int tx = threadIdx.x & 31, ty = threadIdx.x >> 5;  // 32x8
    #pragma unroll
    for (int i = 0; i < 4; i++) {
        int k = k0 + ty + i * 8;
        if (k < INF) tile[ty + i * 8][tx] = w[(size_t)k * DD + n0 + tx];
    }
    __syncthreads();
    #pragma unroll
    for (int i = 0; i < 4; i++) {
        int k = k0 + tx;
        int n = n0 + ty + i * 8;
        if (k < INF)
            wT[(size_t)v * DD * INF + (size_t)n * INF + k] = f2bf(tile[tx][ty + i * 8]);
    }
}

// ---------- projection GEMM, no-LDS no-barrier: h = relu(x_v @ W_v + b) ----------
// 128x128 tile, 4 waves as 2x2; fragments loaded straight from global.
__global__ __launch_bounds__(256) void proj_nl(
    const float* __restrict__ x0, const float* __restrict__ x1, const float* __restrict__ x2,
    const float* __restrict__ b0, const float* __restrict__ b1, const float* __restrict__ b2,
    const unsigned short* __restrict__ wT, unsigned short* __restrict__ hout) {
    int v = blockIdx.y;
    const float* x = (v == 0) ? x0 : ((v == 1) ? x1 : x2);
    const float* bias = (v == 0) ? b0 : ((v == 1) ? b1 : b2);
    const unsigned short* wTv = wT + (size_t)v * DD * INF;

    int t = threadIdx.x, lane = t & 63, wid = t >> 6;
    int wm = wid >> 1, wn = wid & 1;
    int lm = lane & 15, lq = lane >> 4;

    const float* aptr[4];
    #pragma unroll
    for (int i = 0; i < 4; i++) {
        int r = blockIdx.x * 128 + wm * 64 + i * 16 + lm;
        if (r >= NN) r = NN - 1;  // clamp; epilogue guards
        aptr[i] = x + (size_t)r * INF + lq * 8;
    }
    const unsigned short* bptr[4];
    #pragma unroll
    for (int j = 0; j < 4; j++) {
        int c = wn * 64 + j * 16 + lm;
        bptr[j] = wTv + (size_t)c * INF + lq * 8;
    }

    f32x4 acc[4][4];
    #pragma unroll
    for (int i = 0; i < 4; i++)
        #pragma unroll
        for (int j = 0; j < 4; j++) {
            acc[i][j][0] = 0.f; acc[i][j][1] = 0.f; acc[i][j][2] = 0.f; acc[i][j][3] = 0.f;
        }

    #pragma unroll 2
    for (int kk = 0; kk < 62; kk++) {  // k = kk*32 .. +31, all < 1984
        short8 af[4], bfr[4];
        #pragma unroll
        for (int i = 0; i < 4; i++) {
            const float4* p = (const float4*)(aptr[i] + kk * 32);
            af[i] = cvt8(p[0], p[1]);
        }
        #pragma unroll
        for (int j = 0; j < 4; j++)
            bfr[j] = *(const short8*)(bptr[j] + kk * 32);
        #pragma unroll
        for (int i = 0; i < 4; i++)
            #pragma unroll
            for (int j = 0; j < 4; j++)
                acc[i][j] = __builtin_amdgcn_mfma_f32_16x16x32_bf16(af[i], bfr[j], acc[i][j], 0, 0, 0);
    }
    {   // tail: k = 1984..1999 (16 wide) — only lq<2 holds real data
        short8 af[4], bfr[4];
        short8 z = {0, 0, 0, 0, 0, 0, 0, 0};
        #pragma unroll
        for (int i = 0; i < 4; i++) {
            if (lq < 2) {
                const float4* p = (const float4*)(aptr[i] + 62 * 32);
                af[i] = cvt8(p[0], p[1]);
            } else af[i] = z;
        }
        #pragma unroll
        for (int j = 0; j < 4; j++)
            bfr[j] = (lq < 2) ? *(const short8*)(bptr[j] + 62 * 32) : z;
        #pragma unroll
        for (int i = 0; i < 4; i++)
            #pragma unroll
            for (int j = 0; j < 4; j++)
                acc[i][j] = __builtin_amdgcn_mfma_f32_16x16x32_bf16(af[i], bfr[j], acc[i][j], 0, 0, 0);
    }
    // epilogue: C row=(lane>>4)*4+reg, col=lane&15
    #pragma unroll
    for (int i = 0; i < 4; i++) {
        int lr = wm * 64 + i * 16 + lq * 4;
        #pragma unroll
        for (int j = 0; j < 4; j++) {
            int c = wn * 64 + j * 16 + lm;
            float bv = bias[c];
            #pragma unroll
            for (int u = 0; u < 4; u++) {
                int grow = blockIdx.x * 128 + lr + u;
                if (grow < NN) {
                    float o = fmaxf(acc[i][j][u] + bv, 0.f);
                    hout[((size_t)(v * NN + grow)) * DD + c] = f2bf(o);
                }
            }
        }
    }
}

// ---------- xw GEMM, no-LDS: xw[r] = h @ W_r (bf16, K=128) ----------
__global__ __launch_bounds__(256) void xw_nl(
    const unsigned short* __restrict__ h, const unsigned short* __restrict__ wTrel,
    unsigned short* __restrict__ xw) {
    int r = blockIdx.y;
    const unsigned short* wTr = wTrel + (size_t)r * DD * DD;
    int t = threadIdx.x, lane = t & 63, wid = t >> 6;
    int wm = wid >> 1, wn = wid & 1;
    int lm = lane & 15, lq = lane >> 4;

    const unsigned short* aptr[4];
    #pragma unroll
    for (int i = 0; i < 4; i++) {
        int rr = blockIdx.x * 128 + wm * 64 + i * 16 + lm;
        if (rr >= NTT) rr = NTT - 1;
        aptr[i] = h + (size_t)rr * DD + lq * 8;
    }
    const unsigned short* bptr[4];
    #pragma unroll
    for (int j = 0; j < 4; j++) {
        int c = wn * 64 + j * 16 + lm;
        bptr[j] = wTr + (size_t)c * DD + lq * 8;
    }

    f32x4 acc[4][4];
    #pragma unroll
    for (int i = 0; i < 4; i++)
        #pragma unroll
        for (int j = 0; j < 4; j++) {
            acc[i][j][0] = 0.f; acc[i][j][1] = 0.f; acc[i][j][2] = 0.f; acc[i][j][3] = 0.f;
        }

    #pragma unroll
    for (int kk = 0; kk < 4; kk++) {
        short8 af[4], bfr[4];
        #pragma unroll
        for (int i = 0; i < 4; i++) af[i] = *(const short8*)(aptr[i] + kk * 32);
        #pragma unroll
        for (int j = 0; j < 4; j++) bfr[j] = *(const short8*)(bptr[j] + kk * 32);
        #pragma unroll
        for (int i = 0; i < 4; i++)
            #pragma unroll
            for (int j = 0; j < 4; j++)
                acc[i][j] = __builtin_amdgcn_mfma_f32_16x16x32_bf16(af[i], bfr[j], acc[i][j], 0, 0, 0);
    }
    #pragma unroll
    for (int i = 0; i < 4; i++) {
        int lr = wm * 64 + i * 16 + lq * 4;
        #pragma unroll
        for (int j = 0; j < 4; j++) {
            int c = wn * 64 + j * 16 + lm;
            #pragma unroll
            for (int u = 0; u < 4; u++) {
                int g2 = blockIdx.x * 128 + lr + u;
                if (g2 < NTT)
                    xw[((size_t)r * NTT + g2) * DD + c] = f2bf(acc[i][j][u]);
            }
        }
    }
}

// ---------- per-(relation,node) attention scalars ----------
__global__ void qk_nodes(const unsigned short* __restrict__ h, const float* __restrict__ qvec,
                         const float* __restrict__ kvec, float* __restrict__ qn,
                         float* __restrict__ kn) {
    int wid = threadIdx.x >> 6, lane = threadIdx.x & 63;
    int node = blockIdx.x * 4 + wid;
    if (node >= NTT) return;
    unsigned int u = *(const unsigned int*)(h + (size_t)node * DD + lane * 2);
    float h0 = bf2f(u & 0xffff), h1 = bf2f(u >> 16);
    #pragma unroll
    for (int r = 0; r < NR; r++) {
        float pq = h0 * qvec[r * DD + lane * 2] + h1 * qvec[r * DD + lane * 2 + 1];
        float pk = h0 * kvec[r * DD + lane * 2] + h1 * kvec[r * DD + lane * 2 + 1];
        #pragma unroll
        for (int off = 32; off; off >>= 1) {
            pq += __shfl_xor(pq, off);
            pk += __shfl_xor(pk, off);
        }
        if (lane == 0) {
            qn[r * NTT + node] = pq;
            kn[r * NTT + node] = pk;
        }
    }
}

// ---------- CSR build ----------
__global__ void hist(const int* __restrict__ dst, int* __restrict__ indeg) {
    int e = blockIdx.x * 256 + threadIdx.x;
    if (e < NE) atomicAdd(&indeg[dst[e]], 1);
}

__global__ __launch_bounds__(1024) void scan_indeg(const int* __restrict__ indeg,
                                                   int* __restrict__ start) {
    int t = threadIdx.x;
    const int per = (NTT + 1023) / 1024;  // 59
    int base = t * per;
    int s = 0;
    for (int i = 0; i < per; i++) {
        int idx = base + i;
        if (idx < NTT) s += indeg[idx];
    }
    int lane = t & 63, wid = t >> 6;
    __shared__ int wsum[16];
    int v = s;
    #pragma unroll
    for (int off = 1; off < 64; off <<= 1) {
        int u = __shfl_up(v, off);
        if (lane >= off) v += u;
    }
    if (lane == 63) wsum[wid] = v;
    __syncthreads();
    if (t < 16) {
        int w = wsum[t];
        #pragma unroll
        for (int off = 1; off < 16; off <<= 1) {
            int u = __shfl_up(w, off);
            if (t >= off) w += u;
        }
        wsum[t] = w;
    }
    __syncthreads();
    int excl = (v - s) + (wid ? wsum[wid - 1] : 0);
    int run = excl;
    for (int i = 0; i < per; i++) {
        int idx = base + i;
        if (idx < NTT) {
            start[idx] = run;
            run += indeg[idx];
        }
    }
    if (t == 1023) start[NTT] = run;
}

// scatter + per-edge attention weight
__global__ void scatter2(const int* __restrict__ dst, const int* __restrict__ src,
                         const int* __restrict__ typ, const int* __restrict__ start,
                         int* __restrict__ cursor, const float* __restrict__ qn,
                         const float* __restrict__ kn, unsigned int* __restrict__ packed,
                         float* __restrict__ wl) {
    int e = blockIdx.x * 256 + threadIdx.x;
    if (e >= NE) return;
    int d = dst[e], ss = src[e], tt = typ[e];
    float al = qn[tt * NTT + d] + kn[tt * NTT + ss];
    al = (al > 0.f) ? al : 0.2f * al;   // leaky_relu
    float w = __expf(al);               // softmax shift-invariance: no segment_max
    int pos = atomicAdd(&cursor[d], 1);
    int idx = start[d] + pos;
    packed[idx] = (unsigned)ss | ((unsigned)tt << 16);
    wl[idx] = w;
}

// ---------- aggregation: one wave per dst node ----------
__global__ void aggregate(const unsigned int* __restrict__ packed, const float* __restrict__ wl,
                          const int* __restrict__ start, const unsigned short* __restrict__ xw,
                          const float* __restrict__ conv_bias, float* __restrict__ h2) {
    int wid = threadIdx.x >> 6, lane = threadIdx.x & 63;
    int node = blockIdx.x * 4 + wid;
    if (node >= NTT) return;
    int s0 = start[node], s1 = start[node + 1];
    float a0 = 0.f, a1 = 0.f, denom = 0.f;
    for (int base = s0; base < s1; base += 64) {
        int cnt = min(64, s1 - base);
        unsigned pk = 0;
        float wv = 0.f;
        if (lane < cnt) {
            pk = packed[base + lane];
            wv = wl[base + lane];
        }
        denom += wv;
        for (int i = 0; i < cnt; i++) {
            unsigned sp = __shfl(pk, i);
            float sw = __shfl(wv, i);
            unsigned ss = sp & 0xFFFFu;
            unsigned tt = sp >> 16;
            unsigned u = *(const unsigned int*)(xw + ((size_t)tt * NTT + ss) * DD + lane * 2);
            a0 += sw * bf2f(u & 0xffff);
            a1 += sw * bf2f(u >> 16);
        }
    }
    #pragma unroll
    for (int off = 32; off; off >>= 1) denom += __shfl_xor(denom, off);
    float rdenom = 1.f / (denom + 1e-16f);
    float2 o;
    o.x = fmaxf(a0 * rdenom + conv_bias[lane * 2], 0.f);
    o.y = fmaxf(a1 * rdenom + conv_bias[lane * 2 + 1], 0.f);
    *(float2*)&h2[(size_t)node * DD + lane * 2] = o;
}

// ---------- final linear ----------
__global__ void final_linear(const float* __restrict__ h2, const float* __restrict__ w_int,
                             const float* __restrict__ b_int, float* __restrict__ out) {
    int wid = threadIdx.x >> 6, lane = threadIdx.x & 63;
    int node = blockIdx.x * 4 + wid;
    if (node >= NN) return;
    float acc[NL] = {0.f, 0.f, 0.f, 0.f, 0.f};
    for (int j = lane; j < NV * DD; j += 64) {
        int v = j >> 7, d = j & 127;
        float f = h2[((size_t)(v * NN + node)) * DD + d];
        #pragma unroll
        for (int c = 0; c < NL; c++) acc[c] += f * w_int[j * NL + c];
    }
    #pragma unroll
    for (int c = 0; c < NL; c++) {
        float s = acc[c];
        #pragma unroll
        for (int off = 32; off; off >>= 1) s += __shfl_xor(s, off);
        if (lane == 0) out[(size_t)node * NL + c] = s + b_int[c];
    }
}

extern "C" void kernel_launch(void* const* d_in, const int* in_sizes, int n_in, void* d_out,
                              int out_size, void* d_ws, size_t ws_size, hipStream_t stream) {
    (void)in_sizes; (void)n_in; (void)out_size; (void)ws_size;
    const float* x0 = (const float*)d_in[0];
    const float* w0 = (const float*)d_in[1];
    const float* b0 = (const float*)d_in[2];
    const float* x1 = (const float*)d_in[3];
    const float* w1 = (const float*)d_in[4];
    const float* b1 = (const float*)d_in[5];
    const float* x2 = (const float*)d_in[6];
    const float* w2 = (const float*)d_in[7];
    const float* b2 = (const float*)d_in[8];
    const int* esrc = (const int*)d_in[9];
    const int* edst = (const int*)d_in[10];
    const int* etype = (const int*)d_in[11];
    const float* basis = (const float*)d_in[12];
    const float* comp = (const float*)d_in[13];
    const float* att_q = (const float*)d_in[14];
    const float* att_k = (const float*)d_in[15];
    const float* conv_bias = (const float*)d_in[16];
    const float* w_int = (const float*)d_in[17];
    const float* b_int = (const float*)d_in[18];

    char* ws = (char*)d_ws;
    size_t off = 0;
    auto alloc = [&](size_t bytes) -> void* {
        void* p = ws + off;
        off += bytes;
        off = (off + 255) & ~(size_t)255;
        return p;
    };
    unsigned short* h = (unsigned short*)alloc((size_t)NTT * DD * 2);
    unsigned short* xw = (unsigned short*)alloc((size_t)NR * NTT * DD * 2);
    float* qn = (float*)alloc((size_t)NR * NTT * 4);
    float* kn = (float*)alloc((size_t)NR * NTT * 4);
    unsigned short* wT = (unsigned short*)alloc((size_t)NV * DD * INF * 2);
    unsigned short* wTrel = (unsigned short*)alloc((size_t)NR * DD * DD * 2);
    float* qvec = (float*)alloc((size_t)NR * DD * 4);
    float* kvec = (float*)alloc((size_t)NR * DD * 4);
    int* indeg = (int*)alloc((size_t)NTT * 4);
    int* cursor = (int*)alloc((size_t)NTT * 4);
    int* startp = (int*)alloc((size_t)(NTT + 1) * 4);
    unsigned int* packed = (unsigned int*)alloc((size_t)NE * 4);
    float* wl = (float*)alloc((size_t)NE * 4);
    float* h2 = (float*)alloc((size_t)NTT * DD * 4);

    prep_misc<<<390 + (NTT + 255) / 256, 256, 0, stream>>>(basis, comp, att_q, att_k, wTrel,
                                                           qvec, kvec, indeg, cursor);
    prep_wTt<<<dim3((INF + 31) / 32, DD / 32, NV), 256, 0, stream>>>(w0, w1, w2, wT);
    hist<<<(NE + 255) / 256, 256, 0, stream>>>(edst, indeg);
    scan_indeg<<<1, 1024, 0, stream>>>(indeg, startp);

    proj_nl<<<dim3((NN + 127) / 128, NV), 256, 0, stream>>>(x0, x1, x2, b0, b1, b2, wT, h);
    qk_nodes<<<(NTT + 3) / 4, 256, 0, stream>>>(h, qvec, kvec, qn, kn);
    xw_nl<<<dim3((NTT + 127) / 128, NR), 256, 0, stream>>>(h, wTrel, xw);

    scatter2<<<(NE + 255) / 256, 256, 0, stream>>>(edst, esrc, etype, startp, cursor, qn, kn,
                                                   packed, wl);
    aggregate<<<(NTT + 3) / 4, 256, 0, stream>>>(packed, wl, startp, xw, conv_bias, h2);
    final_linear<<<(NN + 3) / 4, 256, 0, stream>>>(h2, w_int, b_int, (float*)d_out);
}